// Round 11
// baseline (312.776 us; speedup 1.0000x reference)
//
#include <hip/hip_runtime.h>

// Chambolle-Pock anisotropic TV prox. B=8, H=W=256, 200 iters, fp32.
//
// Round 11 (= round 10 with the #pragma-in-braces compile fix):
// round-9 structure (T=16 x12 + T=8 x1, ubar-only fp32 LDS dbuf,
// register ghosts, med3 clamp, XCD-quad swizzle, fp16 inter-launch state)
// with the patch widened 2x4 -> 2x8 px/thread:
//   T=16: 32 row-pairs x 12 col-groups = 384 threads (6 waves).
//   Edge b32 reads and row b128s amortize over 2x width: LDS cyc/px -16%,
//   ghost VALU fraction 0.75 -> 0.625. Trades occupancy (12->6 waves) for
//   less per-iter pipe work — discriminates convoy vs latency model.
// Boundary semantics (r3/r6-verified): OOB lam -> 0 -> p,q clamp to 0;
// explicitly zero SHIFTED bounds at pads (p[-1]: bp/bpg when row<0;
// q[:,-1]: bq/bqg when col<0). LDS edge garbage advances 1 cell/iter,
// reaches (never enters) interior after T iters; med3 scrubs NaN.

#define Hc 256
#define Wc 256
#define Bc 8
#define NPIX (Bc * Hc * Wc)          // 524288

typedef _Float16 half8_ __attribute__((ext_vector_type(8)));

constexpr int RRv(int T)   { return 32 + 2 * T; }          // region rows
constexpr int RCv(int T)   { return 64 + 2 * T; }          // region cols
constexpr int NCGv(int T)  { return RCv(T) / 8; }          // 8-wide col groups
constexpr int NACTv(int T) { return (RRv(T) / 2) * NCGv(T); }
constexpr int BLKv(int T)  { return (NACTv(T) + 63) / 64 * 64; }
constexpr int LSTRv(int T) { return (RCv(T) + 2 + 3) / 4 * 4; }  // 16B-mult row stride

constexpr float TAUc = 0.35355339f;
constexpr float SIGc = 0.35355339f;
constexpr float Ac_  = 1.0f / (1.0f + TAUc);
constexpr float Bq_  = TAUc * Ac_;

__device__ __forceinline__ float4 gld4(const float* p, int gi, int gj) {
    if ((unsigned)gi < (unsigned)Hc && (unsigned)gj < (unsigned)Wc)
        return *(const float4*)(p + (gi << 8) + gj);
    return make_float4(0.f, 0.f, 0.f, 0.f);
}
__device__ __forceinline__ float gld1(const float* p, int gi, int gj) {
    if ((unsigned)gi < (unsigned)Hc && (unsigned)gj < (unsigned)Wc)
        return p[(gi << 8) + gj];
    return 0.f;
}
__device__ __forceinline__ half8_ gld8h(const _Float16* p, int gi, int gj) {
    if ((unsigned)gi < (unsigned)Hc && (unsigned)gj < (unsigned)Wc)
        return *(const half8_*)(p + (gi << 8) + gj);
    return half8_{(_Float16)0.f,(_Float16)0.f,(_Float16)0.f,(_Float16)0.f,
                  (_Float16)0.f,(_Float16)0.f,(_Float16)0.f,(_Float16)0.f};
}
__device__ __forceinline__ float gld1h(const _Float16* p, int gi, int gj) {
    if ((unsigned)gi < (unsigned)Hc && (unsigned)gj < (unsigned)Wc)
        return (float)p[(gi << 8) + gj];
    return 0.f;
}
// clamp to [-b, b] in one v_med3_f32; NaN v -> -b (finite, 0 when b==0).
__device__ __forceinline__ float clipf(float v, float b) {
    return __builtin_amdgcn_fmed3f(v, -b, b);
}
__device__ __forceinline__ half8_ toh8(const float* v) {
    return half8_{(_Float16)v[0],(_Float16)v[1],(_Float16)v[2],(_Float16)v[3],
                  (_Float16)v[4],(_Float16)v[5],(_Float16)v[6],(_Float16)v[7]};
}

template <int T, bool FIRST, bool LAST>
__global__ __launch_bounds__(BLKv(T))
void tv_tile(const float* __restrict__ f, const float* __restrict__ lam,
             const _Float16* __restrict__ u_in, const _Float16* __restrict__ ub_in,
             const _Float16* __restrict__ p_in, const _Float16* __restrict__ q_in,
             _Float16* __restrict__ u_out, _Float16* __restrict__ ub_out,
             _Float16* __restrict__ p_out, _Float16* __restrict__ q_out,
             float* __restrict__ fin_out)
{
    constexpr int RR   = RRv(T);
    constexpr int NCG  = NCGv(T);
    constexpr int NACT = NACTv(T);
    constexpr int LSTR = LSTRv(T);

    __shared__ float s_ub[2][RR + 2][LSTR];   // region row x at [.][x+1][.]

    const int t   = threadIdx.x;
    const int blk = blockIdx.x;            // 0..255
    // XCD-quad swizzle: all 4 members of a 2x2 tile quad share blk&7 (XCD).
    const int xc  = blk & 7;
    const int s_  = blk >> 3;
    const int m_  = s_ >> 3;               // member in quad (0..3)
    const int b   = s_ & 7;                // batch
    const int ti  = ((xc >> 1) << 1) | (m_ >> 1);   // 0..7
    const int tj  = ((xc & 1) << 1) | (m_ & 1);     // 0..3
    const int gi0 = ti * 32 - T;
    const int gj0 = tj * 64 - T;
    const int boff = b * (Hc * Wc);

    const bool active = (NACT == BLKv(T)) || (t < NACT);
    const int rp  = t / NCG;
    const int cgv = t - rp * NCG;
    const int r   = rp * 2;                // region row of top row
    const int c0  = cgv * 8;
    const int gi  = gi0 + r;               // global row of top row
    const int gj  = gj0 + c0;

    const float* fb = f + boff;
    const float* lb = lam + boff;

    float u[2][8], ub[2][8], p[2][8], q[2][8], bf[2][8];
    float pg[8], qg[2];                    // ghost p row (gi-1), ghost q col (gj-1)
    float bp[2][8], bpg[8], bq[2][8], bqg[2];

    // ---------------- load phase ----------------
    if (active) {
        float4 a, bv;
        a = gld4(fb, gi, gj); bv = gld4(fb, gi, gj + 4);
        const float fr0[8] = {a.x,a.y,a.z,a.w, bv.x,bv.y,bv.z,bv.w};
        a = gld4(fb, gi + 1, gj); bv = gld4(fb, gi + 1, gj + 4);
        const float fr1[8] = {a.x,a.y,a.z,a.w, bv.x,bv.y,bv.z,bv.w};
        #pragma unroll
        for (int e = 0; e < 8; ++e) { bf[0][e] = Bq_ * fr0[e]; bf[1][e] = Bq_ * fr1[e]; }

        // lam rows gi, gi+1 (cols gj..gj+8), gi+2 (cols gj..gj+7)
        a = gld4(lb, gi, gj); bv = gld4(lb, gi, gj + 4);
        const float l0[9] = {a.x,a.y,a.z,a.w, bv.x,bv.y,bv.z,bv.w, gld1(lb, gi, gj + 8)};
        a = gld4(lb, gi + 1, gj); bv = gld4(lb, gi + 1, gj + 4);
        const float l1[9] = {a.x,a.y,a.z,a.w, bv.x,bv.y,bv.z,bv.w, gld1(lb, gi + 1, gj + 8)};
        a = gld4(lb, gi + 2, gj); bv = gld4(lb, gi + 2, gj + 4);
        const float l2[8] = {a.x,a.y,a.z,a.w, bv.x,bv.y,bv.z,bv.w};

        #pragma unroll
        for (int e = 0; e < 8; ++e) {
            bpg[e]   = l0[e];       // ghost p row bound = lam[gi]
            bq[0][e] = l0[e + 1];   // q row0 bound = lam[gi][gj+e+1]
            bp[0][e] = l1[e];       // p row0 bound = lam[gi+1]
            bq[1][e] = l1[e + 1];
            bp[1][e] = l2[e];       // p row1 bound = lam[gi+2]
        }
        bqg[0] = l0[0]; bqg[1] = l1[0];

        // pad fixes: p[-1,:]=0 and q[:,-1]=0 in the reference; their
        // SHIFTED bounds are in-image there -> zero explicitly.
        if (gi < 0) {
            for (int e = 0; e < 8; ++e) bp[0][e] = 0.f;
        }
        if (gi + 1 < 0) {
            for (int e = 0; e < 8; ++e) bp[1][e] = 0.f;
        }
        if (gi - 1 < 0) {
            for (int e = 0; e < 8; ++e) bpg[e] = 0.f;
        }
        for (int e = 0; e < 8; ++e)
            if (gj + e < 0) { bq[0][e] = 0.f; bq[1][e] = 0.f; }
        if (gj - 1 < 0) { bqg[0] = 0.f; bqg[1] = 0.f; }

        if (FIRST) {
            #pragma unroll
            for (int e = 0; e < 8; ++e) {
                u[0][e] = ub[0][e] = fr0[e];
                u[1][e] = ub[1][e] = fr1[e];
                p[0][e] = p[1][e] = q[0][e] = q[1][e] = pg[e] = 0.f;
            }
            qg[0] = qg[1] = 0.f;
        } else {
            half8_ hv;
            #pragma unroll
            for (int row = 0; row < 2; ++row) {
                hv = gld8h(u_in + boff, gi + row, gj);
                #pragma unroll
                for (int e = 0; e < 8; ++e) u[row][e] = hv[e];
                hv = gld8h(ub_in + boff, gi + row, gj);
                #pragma unroll
                for (int e = 0; e < 8; ++e) ub[row][e] = hv[e];
                hv = gld8h(p_in + boff, gi + row, gj);
                #pragma unroll
                for (int e = 0; e < 8; ++e) p[row][e] = hv[e];
                hv = gld8h(q_in + boff, gi + row, gj);
                #pragma unroll
                for (int e = 0; e < 8; ++e) q[row][e] = hv[e];
            }
            hv = gld8h(p_in + boff, gi - 1, gj);
            #pragma unroll
            for (int e = 0; e < 8; ++e) pg[e] = hv[e];
            qg[0] = gld1h(q_in + boff, gi,     gj - 1);
            qg[1] = gld1h(q_in + boff, gi + 1, gj - 1);
        }

        *(float4*)&s_ub[0][r + 1][c0]     = make_float4(ub[0][0], ub[0][1], ub[0][2], ub[0][3]);
        *(float4*)&s_ub[0][r + 1][c0 + 4] = make_float4(ub[0][4], ub[0][5], ub[0][6], ub[0][7]);
        *(float4*)&s_ub[0][r + 2][c0]     = make_float4(ub[1][0], ub[1][1], ub[1][2], ub[1][3]);
        *(float4*)&s_ub[0][r + 2][c0 + 4] = make_float4(ub[1][4], ub[1][5], ub[1][6], ub[1][7]);
    }
    __syncthreads();

    // ---------------- T fused iterations, 1 barrier each ----------------
    auto iter_step = [&](int cur) {
        const int nxt = cur ^ 1;
        if (active) {
            const float4 m1a = *(const float4*)&s_ub[cur][r][c0];
            const float4 m1b = *(const float4*)&s_ub[cur][r][c0 + 4];
            const float4 p2a = *(const float4*)&s_ub[cur][r + 3][c0];
            const float4 p2b = *(const float4*)&s_ub[cur][r + 3][c0 + 4];
            const float  ubre0 = s_ub[cur][r + 1][c0 + 8];
            const float  ubre1 = s_ub[cur][r + 2][c0 + 8];
            const float  uble0 = s_ub[cur][r + 1][c0 - 1];
            const float  uble1 = s_ub[cur][r + 2][c0 - 1];
            const float ubm1[8] = {m1a.x,m1a.y,m1a.z,m1a.w, m1b.x,m1b.y,m1b.z,m1b.w};
            const float ubp2[8] = {p2a.x,p2a.y,p2a.z,p2a.w, p2b.x,p2b.y,p2b.z,p2b.w};

            // ---- step 1: p, q, ghosts (from prev-iter ubar) ----
            #pragma unroll
            for (int e = 0; e < 8; ++e) {
                pg[e]   = clipf(fmaf(SIGc, ub[0][e] - ubm1[e],  pg[e]),   bpg[e]);
                p[0][e] = clipf(fmaf(SIGc, ub[1][e] - ub[0][e], p[0][e]), bp[0][e]);
                p[1][e] = clipf(fmaf(SIGc, ubp2[e]  - ub[1][e], p[1][e]), bp[1][e]);
            }
            qg[0] = clipf(fmaf(SIGc, ub[0][0] - uble0, qg[0]), bqg[0]);
            qg[1] = clipf(fmaf(SIGc, ub[1][0] - uble1, qg[1]), bqg[1]);
            #pragma unroll
            for (int e = 0; e < 8; ++e) {
                const float nx0 = (e < 7) ? ub[0][e + 1] : ubre0;
                const float nx1 = (e < 7) ? ub[1][e + 1] : ubre1;
                q[0][e] = clipf(fmaf(SIGc, nx0 - ub[0][e], q[0][e]), bq[0][e]);
                q[1][e] = clipf(fmaf(SIGc, nx1 - ub[1][e], q[1][e]), bq[1][e]);
            }

            // ---- step 2: u, ubar ----
            #pragma unroll
            for (int e = 0; e < 8; ++e) {
                const float ql0 = (e == 0) ? qg[0] : q[0][e - 1];
                const float dv0 = (pg[e] - p[0][e]) + (ql0 - q[0][e]);
                const float un0 = fmaf(-Bq_, dv0, fmaf(Ac_, u[0][e], bf[0][e]));
                ub[0][e] = 2.f * un0 - u[0][e]; u[0][e] = un0;

                const float ql1 = (e == 0) ? qg[1] : q[1][e - 1];
                const float dv1 = (p[0][e] - p[1][e]) + (ql1 - q[1][e]);
                const float un1 = fmaf(-Bq_, dv1, fmaf(Ac_, u[1][e], bf[1][e]));
                ub[1][e] = 2.f * un1 - u[1][e]; u[1][e] = un1;
            }

            *(float4*)&s_ub[nxt][r + 1][c0]     = make_float4(ub[0][0], ub[0][1], ub[0][2], ub[0][3]);
            *(float4*)&s_ub[nxt][r + 1][c0 + 4] = make_float4(ub[0][4], ub[0][5], ub[0][6], ub[0][7]);
            *(float4*)&s_ub[nxt][r + 2][c0]     = make_float4(ub[1][0], ub[1][1], ub[1][2], ub[1][3]);
            *(float4*)&s_ub[nxt][r + 2][c0 + 4] = make_float4(ub[1][4], ub[1][5], ub[1][6], ub[1][7]);
        }
        __syncthreads();
    };

    for (int kk = 0; kk < T / 2; ++kk) { iter_step(0); iter_step(1); }

    // ---------------- store phase (interior only) ----------------
    if (active && r >= T && r < T + 32 && cgv >= T / 8 && cgv < T / 8 + 8) {
        const int idx0 = boff + (gi << 8) + gj;
        const int idx1 = idx0 + Wc;
        if (LAST) {
            *(float4*)&fin_out[idx0]     = make_float4(u[0][0], u[0][1], u[0][2], u[0][3]);
            *(float4*)&fin_out[idx0 + 4] = make_float4(u[0][4], u[0][5], u[0][6], u[0][7]);
            *(float4*)&fin_out[idx1]     = make_float4(u[1][0], u[1][1], u[1][2], u[1][3]);
            *(float4*)&fin_out[idx1 + 4] = make_float4(u[1][4], u[1][5], u[1][6], u[1][7]);
        } else {
            *(half8_*)&u_out [idx0] = toh8(u[0]);
            *(half8_*)&u_out [idx1] = toh8(u[1]);
            *(half8_*)&ub_out[idx0] = toh8(ub[0]);
            *(half8_*)&ub_out[idx1] = toh8(ub[1]);
            *(half8_*)&p_out [idx0] = toh8(p[0]);
            *(half8_*)&p_out [idx1] = toh8(p[1]);
            *(half8_*)&q_out [idx0] = toh8(q[0]);
            *(half8_*)&q_out [idx1] = toh8(q[1]);
        }
    }
}

extern "C" void kernel_launch(void* const* d_in, const int* in_sizes, int n_in,
                              void* d_out, int out_size, void* d_ws, size_t ws_size,
                              hipStream_t stream)
{
    const float* f   = (const float*)d_in[0];
    const float* lam = (const float*)d_in[1];
    _Float16* ws = (_Float16*)d_ws;      // 8 half arrays = 8 MB

    _Float16* U [2] = { ws + 0 * (size_t)NPIX, ws + 4 * (size_t)NPIX };
    _Float16* UB[2] = { ws + 1 * (size_t)NPIX, ws + 5 * (size_t)NPIX };
    _Float16* P [2] = { ws + 2 * (size_t)NPIX, ws + 6 * (size_t)NPIX };
    _Float16* Q [2] = { ws + 3 * (size_t)NPIX, ws + 7 * (size_t)NPIX };

    dim3 grid(256);

    // 12 launches of T=16 (iters 0..191) + 1 launch of T=8 (iters 192..199)
    tv_tile<16, true, false><<<grid, dim3(BLKv(16)), 0, stream>>>(
        f, lam, nullptr, nullptr, nullptr, nullptr,
        U[0], UB[0], P[0], Q[0], nullptr);

    for (int l = 1; l < 12; ++l) {
        const int w = l & 1, r = w ^ 1;
        tv_tile<16, false, false><<<grid, dim3(BLKv(16)), 0, stream>>>(
            f, lam, U[r], UB[r], P[r], Q[r],
            U[w], UB[w], P[w], Q[w], nullptr);
    }

    // launch 11 wrote set 1; final T=8 launch reads set 1, writes u -> d_out
    tv_tile<8, false, true><<<grid, dim3(BLKv(8)), 0, stream>>>(
        f, lam, U[1], UB[1], P[1], Q[1],
        nullptr, nullptr, nullptr, nullptr, (float*)d_out);
}

// Round 12
// 239.430 us; speedup vs baseline: 1.3063x; 1.3063x over previous
//
#include <hip/hip_runtime.h>

// Chambolle-Pock anisotropic TV prox. B=8, H=W=256, 200 iters, fp32.
//
// Round 12: revert to round-9 champion (2x4 patch/thread, 768 threads =
// 12 waves/CU — r11 proved the loop is LATENCY-bound: 6 waves exposed the
// ~300cyc barrier+LDS chain, +25%) with two arithmetic-identical tweaks:
//  (1) AoS fp16 state: one 32-B record per 4-px group holds (u,ub,p,q).
//      Load: 2 paired half8 loads/row (was 4 half4 loads); ghost pg =
//      half4 at rec+8, qg = scalar at rec+15. Store: 4 insts (was 8).
//      Fewer VMEM insts AND fewer exposed latencies; fully coalesced.
//  (2) last iteration skips the dead LDS publish + barrier.
// Geometry: T=16 x12 + T=8 x1, interior 32x64, region (32+2T)x(64+2T),
// grid 256 = 1 block/CU, XCD-quad swizzle, med3 clamp, ubar-only fp32 LDS.
// Boundary semantics (r3/r6-verified): OOB loads -> 0 -> p,q clamp to 0;
// explicitly zero SHIFTED clamp bounds at pads (p[-1]: bp/bpg when row<0;
// q[:,-1]: bq/bqg when col<0). LDS edge garbage advances 1 cell/iter,
// reaches (never enters) interior after T iters; med3 scrubs NaN.

#define Hc 256
#define Wc 256
#define Bc 8
#define NPIX (Bc * Hc * Wc)          // 524288

typedef _Float16 half8_ __attribute__((ext_vector_type(8)));
typedef _Float16 half4_ __attribute__((ext_vector_type(4)));

constexpr int RRv(int T)   { return 32 + 2 * T; }          // region rows
constexpr int RCv(int T)   { return 64 + 2 * T; }          // region cols
constexpr int NCGv(int T)  { return RCv(T) / 4; }          // 4-wide col groups
constexpr int NACTv(int T) { return (RRv(T) / 2) * NCGv(T); }
constexpr int BLKv(int T)  { return (NACTv(T) + 63) / 64 * 64; }
constexpr int LSTRv(int T) { return (RCv(T) + 2 + 3) / 4 * 4; }

constexpr float TAUc = 0.35355339f;
constexpr float SIGc = 0.35355339f;
constexpr float Ac_  = 1.0f / (1.0f + TAUc);
constexpr float Bq_  = TAUc * Ac_;

__device__ __forceinline__ float4 gld4(const float* p, int gi, int gj) {
    if ((unsigned)gi < (unsigned)Hc && (unsigned)gj < (unsigned)Wc)
        return *(const float4*)(p + (gi << 8) + gj);
    return make_float4(0.f, 0.f, 0.f, 0.f);
}
__device__ __forceinline__ float gld1(const float* p, int gi, int gj) {
    if ((unsigned)gi < (unsigned)Hc && (unsigned)gj < (unsigned)Wc)
        return p[(gi << 8) + gj];
    return 0.f;
}
// clamp to [-b, b] in one v_med3_f32; NaN v -> -b (finite, 0 when b==0).
__device__ __forceinline__ float clipf(float v, float b) {
    return __builtin_amdgcn_fmed3f(v, -b, b);
}

// ---- AoS state record: 16 halfs = [u0..3, ub0..3, p0..3, q0..3] per
// 4-px group. Record index: b*16384 + gi*64 + gjg (gjg = gj/4). ----
__device__ __forceinline__ void ldrec(const _Float16* S, int boff4, int gi, int gjg,
                                      float* u, float* ub, float* p, float* q) {
    if ((unsigned)gi < 256u && (unsigned)gjg < 64u) {
        const _Float16* rp = S + (size_t)(boff4 + (gi << 6) + gjg) * 16;
        const half8_ a = *(const half8_*)rp;
        const half8_ b = *(const half8_*)(rp + 8);
        #pragma unroll
        for (int e = 0; e < 4; ++e) { u[e] = a[e]; ub[e] = a[e + 4]; p[e] = b[e]; q[e] = b[e + 4]; }
    } else {
        #pragma unroll
        for (int e = 0; e < 4; ++e) { u[e] = 0.f; ub[e] = 0.f; p[e] = 0.f; q[e] = 0.f; }
    }
}
__device__ __forceinline__ void ldpg(const _Float16* S, int boff4, int gi, int gjg, float* pg) {
    if ((unsigned)gi < 256u && (unsigned)gjg < 64u) {
        const half4_ v = *(const half4_*)(S + (size_t)(boff4 + (gi << 6) + gjg) * 16 + 8);
        #pragma unroll
        for (int e = 0; e < 4; ++e) pg[e] = v[e];
    } else {
        #pragma unroll
        for (int e = 0; e < 4; ++e) pg[e] = 0.f;
    }
}
__device__ __forceinline__ float ldqg(const _Float16* S, int boff4, int gi, int gjg) {
    if ((unsigned)gi < 256u && (unsigned)gjg < 64u)
        return (float)S[(size_t)(boff4 + (gi << 6) + gjg) * 16 + 15];
    return 0.f;
}
__device__ __forceinline__ void strec(_Float16* S, int boff4, int gi, int gjg,
                                      const float* u, const float* ub,
                                      const float* p, const float* q) {
    _Float16* rp = S + (size_t)(boff4 + (gi << 6) + gjg) * 16;
    *(half8_*)rp = half8_{(_Float16)u[0],(_Float16)u[1],(_Float16)u[2],(_Float16)u[3],
                          (_Float16)ub[0],(_Float16)ub[1],(_Float16)ub[2],(_Float16)ub[3]};
    *(half8_*)(rp + 8) = half8_{(_Float16)p[0],(_Float16)p[1],(_Float16)p[2],(_Float16)p[3],
                                (_Float16)q[0],(_Float16)q[1],(_Float16)q[2],(_Float16)q[3]};
}

template <int T, bool FIRST, bool LAST>
__global__ __launch_bounds__(BLKv(T))
void tv_tile(const float* __restrict__ f, const float* __restrict__ lam,
             const _Float16* __restrict__ st_in, _Float16* __restrict__ st_out,
             float* __restrict__ fin_out)
{
    constexpr int RR   = RRv(T);
    constexpr int NCG  = NCGv(T);
    constexpr int NACT = NACTv(T);
    constexpr int LSTR = LSTRv(T);

    __shared__ float s_ub[2][RR + 2][LSTR];   // region row x at [.][x+1][.]

    const int t   = threadIdx.x;
    const int blk = blockIdx.x;            // 0..255
    // XCD-quad swizzle: all 4 members of a 2x2 tile quad share blk&7 (XCD).
    const int xc  = blk & 7;
    const int s_  = blk >> 3;
    const int m_  = s_ >> 3;               // member in quad (0..3)
    const int b   = s_ & 7;                // batch
    const int ti  = ((xc >> 1) << 1) | (m_ >> 1);   // 0..7
    const int tj  = ((xc & 1) << 1) | (m_ & 1);     // 0..3
    const int gi0 = ti * 32 - T;
    const int gj0 = tj * 64 - T;
    const int boff  = b * (Hc * Wc);
    const int boff4 = b * (Hc * Wc / 4);

    const bool active = (NACT == BLKv(T)) || (t < NACT);
    const int rp  = t / NCG;
    const int cgv = t - rp * NCG;
    const int r   = rp * 2;                // region row of top row
    const int c0  = cgv * 4;
    const int gi  = gi0 + r;               // global row of top row
    const int gj  = gj0 + c0;
    const int gjg = gj >> 2;               // 4-aligned, exact

    const float* fb = f + boff;
    const float* lb = lam + boff;

    float u[2][4], ub[2][4], p[2][4], q[2][4], bf[2][4];
    float pg[4], qg[2];                    // ghost p row (gi-1), ghost q col (gj-1)
    float bp[2][4], bpg[4], bq[2][4], bqg[2];

    // ---------------- load phase ----------------
    if (active) {
        float4 v0 = gld4(fb, gi, gj), v1 = gld4(fb, gi + 1, gj);
        bf[0][0] = Bq_ * v0.x; bf[0][1] = Bq_ * v0.y; bf[0][2] = Bq_ * v0.z; bf[0][3] = Bq_ * v0.w;
        bf[1][0] = Bq_ * v1.x; bf[1][1] = Bq_ * v1.y; bf[1][2] = Bq_ * v1.z; bf[1][3] = Bq_ * v1.w;
        const float4 fr0 = v0, fr1 = v1;

        float4 l0 = gld4(lb, gi, gj);     const float l04 = gld1(lb, gi, gj + 4);
        float4 l1 = gld4(lb, gi + 1, gj); const float l14 = gld1(lb, gi + 1, gj + 4);
        float4 l2 = gld4(lb, gi + 2, gj);
        bpg[0] = l0.x; bpg[1] = l0.y; bpg[2] = l0.z; bpg[3] = l0.w;   // ghost p bound = lam[gi]
        bq[0][0] = l0.y; bq[0][1] = l0.z; bq[0][2] = l0.w; bq[0][3] = l04;
        bqg[0] = l0.x;
        bp[0][0] = l1.x; bp[0][1] = l1.y; bp[0][2] = l1.z; bp[0][3] = l1.w;  // p row gi bound
        bq[1][0] = l1.y; bq[1][1] = l1.z; bq[1][2] = l1.w; bq[1][3] = l14;
        bqg[1] = l1.x;
        bp[1][0] = l2.x; bp[1][1] = l2.y; bp[1][2] = l2.z; bp[1][3] = l2.w;  // p row gi+1 bound

        // pad fixes: p[-1,:]=0 and q[:,-1]=0 in the reference; their
        // SHIFTED bounds are in-image there -> zero explicitly.
        if (gi < 0) {
            bp[0][0] = bp[0][1] = bp[0][2] = bp[0][3] = 0.f;
        }
        if (gi + 1 < 0) {
            bp[1][0] = bp[1][1] = bp[1][2] = bp[1][3] = 0.f;
        }
        if (gi - 1 < 0) {
            bpg[0] = bpg[1] = bpg[2] = bpg[3] = 0.f;
        }
        #pragma unroll
        for (int e = 0; e < 4; ++e)
            if (gj + e < 0) { bq[0][e] = 0.f; bq[1][e] = 0.f; }
        if (gj - 1 < 0) { bqg[0] = 0.f; bqg[1] = 0.f; }

        if (FIRST) {
            u[0][0] = ub[0][0] = fr0.x; u[0][1] = ub[0][1] = fr0.y;
            u[0][2] = ub[0][2] = fr0.z; u[0][3] = ub[0][3] = fr0.w;
            u[1][0] = ub[1][0] = fr1.x; u[1][1] = ub[1][1] = fr1.y;
            u[1][2] = ub[1][2] = fr1.z; u[1][3] = ub[1][3] = fr1.w;
            #pragma unroll
            for (int e = 0; e < 4; ++e) { p[0][e] = p[1][e] = q[0][e] = q[1][e] = pg[e] = 0.f; }
            qg[0] = qg[1] = 0.f;
        } else {
            ldrec(st_in, boff4, gi,     gjg, u[0], ub[0], p[0], q[0]);
            ldrec(st_in, boff4, gi + 1, gjg, u[1], ub[1], p[1], q[1]);
            ldpg (st_in, boff4, gi - 1, gjg, pg);
            qg[0] = ldqg(st_in, boff4, gi,     gjg - 1);
            qg[1] = ldqg(st_in, boff4, gi + 1, gjg - 1);
        }

        *(float4*)&s_ub[0][r + 1][c0] = make_float4(ub[0][0], ub[0][1], ub[0][2], ub[0][3]);
        *(float4*)&s_ub[0][r + 2][c0] = make_float4(ub[1][0], ub[1][1], ub[1][2], ub[1][3]);
    }
    __syncthreads();

    // ---------- T fused iterations, 1 barrier each (none after last) ----------
    auto iter_step = [&](int cur, bool publish) {
        const int nxt = cur ^ 1;
        if (active) {
            const float4 ubm1 = *(const float4*)&s_ub[cur][r][c0];      // row r-1
            const float4 ubp2 = *(const float4*)&s_ub[cur][r + 3][c0];  // row r+2
            const float  ubre0 = s_ub[cur][r + 1][c0 + 4];
            const float  ubre1 = s_ub[cur][r + 2][c0 + 4];
            const float  uble0 = s_ub[cur][r + 1][c0 - 1];
            const float  uble1 = s_ub[cur][r + 2][c0 - 1];

            // ---- step 1: p, q, ghosts (from prev-iter ubar) ----
            pg[0] = clipf(fmaf(SIGc, ub[0][0] - ubm1.x, pg[0]), bpg[0]);
            pg[1] = clipf(fmaf(SIGc, ub[0][1] - ubm1.y, pg[1]), bpg[1]);
            pg[2] = clipf(fmaf(SIGc, ub[0][2] - ubm1.z, pg[2]), bpg[2]);
            pg[3] = clipf(fmaf(SIGc, ub[0][3] - ubm1.w, pg[3]), bpg[3]);

            p[0][0] = clipf(fmaf(SIGc, ub[1][0] - ub[0][0], p[0][0]), bp[0][0]);
            p[0][1] = clipf(fmaf(SIGc, ub[1][1] - ub[0][1], p[0][1]), bp[0][1]);
            p[0][2] = clipf(fmaf(SIGc, ub[1][2] - ub[0][2], p[0][2]), bp[0][2]);
            p[0][3] = clipf(fmaf(SIGc, ub[1][3] - ub[0][3], p[0][3]), bp[0][3]);

            p[1][0] = clipf(fmaf(SIGc, ubp2.x - ub[1][0], p[1][0]), bp[1][0]);
            p[1][1] = clipf(fmaf(SIGc, ubp2.y - ub[1][1], p[1][1]), bp[1][1]);
            p[1][2] = clipf(fmaf(SIGc, ubp2.z - ub[1][2], p[1][2]), bp[1][2]);
            p[1][3] = clipf(fmaf(SIGc, ubp2.w - ub[1][3], p[1][3]), bp[1][3]);

            qg[0] = clipf(fmaf(SIGc, ub[0][0] - uble0, qg[0]), bqg[0]);
            qg[1] = clipf(fmaf(SIGc, ub[1][0] - uble1, qg[1]), bqg[1]);

            q[0][0] = clipf(fmaf(SIGc, ub[0][1] - ub[0][0], q[0][0]), bq[0][0]);
            q[0][1] = clipf(fmaf(SIGc, ub[0][2] - ub[0][1], q[0][1]), bq[0][1]);
            q[0][2] = clipf(fmaf(SIGc, ub[0][3] - ub[0][2], q[0][2]), bq[0][2]);
            q[0][3] = clipf(fmaf(SIGc, ubre0    - ub[0][3], q[0][3]), bq[0][3]);

            q[1][0] = clipf(fmaf(SIGc, ub[1][1] - ub[1][0], q[1][0]), bq[1][0]);
            q[1][1] = clipf(fmaf(SIGc, ub[1][2] - ub[1][1], q[1][1]), bq[1][1]);
            q[1][2] = clipf(fmaf(SIGc, ub[1][3] - ub[1][2], q[1][2]), bq[1][2]);
            q[1][3] = clipf(fmaf(SIGc, ubre1    - ub[1][3], q[1][3]), bq[1][3]);

            // ---- step 2: u, ubar ----
            float dv, un;
            dv = (pg[0] - p[0][0]) + (qg[0]   - q[0][0]);
            un = fmaf(-Bq_, dv, fmaf(Ac_, u[0][0], bf[0][0]));
            ub[0][0] = 2.f * un - u[0][0]; u[0][0] = un;
            dv = (pg[1] - p[0][1]) + (q[0][0] - q[0][1]);
            un = fmaf(-Bq_, dv, fmaf(Ac_, u[0][1], bf[0][1]));
            ub[0][1] = 2.f * un - u[0][1]; u[0][1] = un;
            dv = (pg[2] - p[0][2]) + (q[0][1] - q[0][2]);
            un = fmaf(-Bq_, dv, fmaf(Ac_, u[0][2], bf[0][2]));
            ub[0][2] = 2.f * un - u[0][2]; u[0][2] = un;
            dv = (pg[3] - p[0][3]) + (q[0][2] - q[0][3]);
            un = fmaf(-Bq_, dv, fmaf(Ac_, u[0][3], bf[0][3]));
            ub[0][3] = 2.f * un - u[0][3]; u[0][3] = un;

            dv = (p[0][0] - p[1][0]) + (qg[1]   - q[1][0]);
            un = fmaf(-Bq_, dv, fmaf(Ac_, u[1][0], bf[1][0]));
            ub[1][0] = 2.f * un - u[1][0]; u[1][0] = un;
            dv = (p[0][1] - p[1][1]) + (q[1][0] - q[1][1]);
            un = fmaf(-Bq_, dv, fmaf(Ac_, u[1][1], bf[1][1]));
            ub[1][1] = 2.f * un - u[1][1]; u[1][1] = un;
            dv = (p[0][2] - p[1][2]) + (q[1][1] - q[1][2]);
            un = fmaf(-Bq_, dv, fmaf(Ac_, u[1][2], bf[1][2]));
            ub[1][2] = 2.f * un - u[1][2]; u[1][2] = un;
            dv = (p[0][3] - p[1][3]) + (q[1][2] - q[1][3]);
            un = fmaf(-Bq_, dv, fmaf(Ac_, u[1][3], bf[1][3]));
            ub[1][3] = 2.f * un - u[1][3]; u[1][3] = un;

            if (publish) {
                *(float4*)&s_ub[nxt][r + 1][c0] = make_float4(ub[0][0], ub[0][1], ub[0][2], ub[0][3]);
                *(float4*)&s_ub[nxt][r + 2][c0] = make_float4(ub[1][0], ub[1][1], ub[1][2], ub[1][3]);
            }
        }
        if (publish) __syncthreads();
    };

    #pragma unroll
    for (int k = 0; k < T; ++k) iter_step(k & 1, k != T - 1);

    // ---------------- store phase (interior only) ----------------
    if (active && r >= T && r < T + 32 && cgv >= T / 4 && cgv < T / 4 + 16) {
        if (LAST) {
            const int idx0 = boff + (gi << 8) + gj;
            *(float4*)&fin_out[idx0]      = make_float4(u[0][0], u[0][1], u[0][2], u[0][3]);
            *(float4*)&fin_out[idx0 + Wc] = make_float4(u[1][0], u[1][1], u[1][2], u[1][3]);
        } else {
            strec(st_out, boff4, gi,     gjg, u[0], ub[0], p[0], q[0]);
            strec(st_out, boff4, gi + 1, gjg, u[1], ub[1], p[1], q[1]);
        }
    }
}

extern "C" void kernel_launch(void* const* d_in, const int* in_sizes, int n_in,
                              void* d_out, int out_size, void* d_ws, size_t ws_size,
                              hipStream_t stream)
{
    const float* f   = (const float*)d_in[0];
    const float* lam = (const float*)d_in[1];
    _Float16* ws = (_Float16*)d_ws;

    // two AoS record sets, each NPIX/4 records x 32 B = 4 MB
    _Float16* S[2] = { ws, ws + (size_t)NPIX * 4 };

    dim3 grid(256);

    // 12 launches of T=16 (iters 0..191) + 1 launch of T=8 (iters 192..199)
    tv_tile<16, true, false><<<grid, dim3(BLKv(16)), 0, stream>>>(
        f, lam, nullptr, S[0], nullptr);

    for (int l = 1; l < 12; ++l) {
        const int w = l & 1;
        tv_tile<16, false, false><<<grid, dim3(BLKv(16)), 0, stream>>>(
            f, lam, S[w ^ 1], S[w], nullptr);
    }

    // launch 11 wrote S[1]; final T=8 launch reads S[1], writes u -> d_out
    tv_tile<8, false, true><<<grid, dim3(BLKv(8)), 0, stream>>>(
        f, lam, S[1], nullptr, (float*)d_out);
}